// Round 24
// baseline (205.290 us; speedup 1.0000x reference)
//
#include <hip/hip_runtime.h>
#include <hip/hip_bf16.h>

// GAT 2-layer, N=50000, E=800000, D=128, H=2, F=128, C=H*F=256.
// Round 24: binAx MLP boost — 2 independent edge chains per thread (r23
// counters: VALU 10%, occ 70% => latency-bound on the load->atomic->store
// chain). Block covers 512 edges (e0=b*512+t, e1=e0+256); class=b&7 kept.
// Everything else byte-identical to round 23 (204.5us state).

#define NEG_SLOPE 0.2f
#define SEG_CAP 160

typedef __attribute__((ext_vector_type(8))) short bf16x8_t;
typedef __attribute__((ext_vector_type(4))) float f32x4_t;

__device__ __forceinline__ unsigned short f2bf(float f) {
  union { float f; unsigned int u; } v; v.f = f;
  unsigned int r = v.u + 0x7FFFu + ((v.u >> 16) & 1u);
  return (unsigned short)(r >> 16);
}
__device__ __forceinline__ float bfbits(unsigned int hi16) {
  union { unsigned int u; float f; } v; v.u = hi16;
  return v.f;
}

// ---------------- init: wpack + wal/war + bcur2 segment bases + tstate -------

__global__ __launch_bounds__(256) void init_kernel(
    const float* __restrict__ Ws, const float* __restrict__ als,
    const float* __restrict__ ars,
    unsigned short* __restrict__ Whi, unsigned short* __restrict__ Wlo,
    float* __restrict__ wal, float* __restrict__ war,
    int* __restrict__ bcur2, unsigned int* __restrict__ tstate,
    int n, int nb32)
{
  const int b = blockIdx.x;
  const int t = threadIdx.x;
  if (b < 32) {
    int tg = b * 256 + t;
    int t2 = tg & 4095;
    int lane = t2 & 63;
    int ct3 = (t2 >> 6) & 7;
    int s = (t2 >> 9) & 3;
    int hb = (t2 >> 11) & 1;
    int lay = tg >> 12;
    int col = hb * 128 + ct3 * 16 + (lane & 15);
    int kbase = s * 32 + (lane >> 4) * 8;
    size_t obase = (size_t)lay * 32768 + (size_t)hb * 16384 + (size_t)(t2 & 2047) * 8;
    #pragma unroll
    for (int j = 0; j < 8; ++j) {
      float w = Ws[(size_t)lay * 32768 + (size_t)(kbase + j) * 256 + col];
      unsigned short hb16 = f2bf(w);
      float rem = w - bfbits((unsigned int)hb16 << 16);
      Whi[obase + j] = hb16;
      Wlo[obase + j] = f2bf(rem);
    }
  } else if (b < 36) {
    int tg = (b - 32) * 256 + t;           // 0..1023
    int lr = tg >> 9;
    int rem = tg & 511;
    int lay = rem >> 8, h = (rem >> 7) & 1, k = rem & 127;
    const float* a = (lr ? ars : als) + (size_t)lay * 256 + h * 128;
    const float* wrow = Ws + (size_t)lay * 32768 + (size_t)k * 256 + h * 128;
    float sum = 0.f;
    for (int f = 0; f < 128; ++f) sum = fmaf(wrow[f], a[f], sum);
    (lr ? war : wal)[(size_t)lay * 256 + h * 128 + k] = sum;
  } else {
    int idx = (b - 36) * 256 + t;
    if (idx < nb32 * 8) {
      int c = idx / nb32;
      int bb = idx - c * nb32;
      bcur2[idx] = (bb * 8 + c) * SEG_CAP;   // segment base, bucket-major
    }
    if (idx < 512) tstate[idx] = 0u;
  }
}

// ---------------- binA (2 edges/thread) + xprep fused ----------------
// Blocks [0,histBlocks2): each thread appends edges e0=b*512+t and e1=e0+256
// into their (bucket32, class=b&7) segments — two independent atomic chains
// in flight. Blocks after: xprep (x->bf16 pack + layer-1 el/er).

__global__ __launch_bounds__(256) void binAx_kernel(
    const int* __restrict__ src, const int* __restrict__ dst,
    int* __restrict__ bcur2, unsigned int* __restrict__ tmp,
    int nb32, int n_edges, int histBlocks2,
    const float* __restrict__ x, const float* __restrict__ wal,
    const float* __restrict__ war, unsigned short* __restrict__ xb16,
    float* __restrict__ el, float* __restrict__ er, int n)
{
  const int b = blockIdx.x;
  if (b < histBlocks2) {
    const int cls = (b & 7) * nb32;
    int e0 = b * 512 + threadIdx.x;
    int e1 = e0 + 256;
    bool v0 = e0 < n_edges, v1 = e1 < n_edges;
    int d0 = 0, d1 = 0, s0 = 0, s1 = 0;
    if (v0) { d0 = dst[e0]; s0 = src[e0]; }
    if (v1) { d1 = dst[e1]; s1 = src[e1]; }
    int p0 = 0, p1 = 0;
    if (v0) p0 = atomicAdd(&bcur2[cls + (d0 >> 5)], 1);
    if (v1) p1 = atomicAdd(&bcur2[cls + (d1 >> 5)], 1);
    if (v0) tmp[p0] = ((unsigned int)(d0 & 127) << 16) | (unsigned int)s0;
    if (v1) tmp[p1] = ((unsigned int)(d1 & 127) << 16) | (unsigned int)s1;
    return;
  }
  int node = (b - histBlocks2) * 4 + (threadIdx.x >> 6);
  int c = threadIdx.x & 63;
  if (node >= n) return;
  float2 v = *(const float2*)&x[(size_t)node * 128 + c * 2];
  unsigned int pk = (unsigned int)f2bf(v.x) | ((unsigned int)f2bf(v.y) << 16);
  *(unsigned int*)&xb16[(size_t)node * 128 + c * 2] = pk;
  float pl0 = v.x * wal[2 * c] + v.y * wal[2 * c + 1];
  float pl1 = v.x * wal[128 + 2 * c] + v.y * wal[128 + 2 * c + 1];
  float pr0 = v.x * war[2 * c] + v.y * war[2 * c + 1];
  float pr1 = v.x * war[128 + 2 * c] + v.y * war[128 + 2 * c + 1];
  #pragma unroll
  for (int off = 1; off < 64; off <<= 1) {
    pl0 += __shfl_xor(pl0, off);
    pl1 += __shfl_xor(pl1, off);
    pr0 += __shfl_xor(pr0, off);
    pr1 += __shfl_xor(pr1, off);
  }
  if (c == 0) {
    *(float2*)&el[(size_t)node * 2] = make_float2(pl0, pl1);
    *(float2*)&er[(size_t)node * 2] = make_float2(pr0, pr1);
  }
}

// ---------------- binB: fills -> LDS hist -> lookback prefix -> offsets/srcp -

__global__ __launch_bounds__(256) void binB_kernel(
    const unsigned int* __restrict__ tmp, const int* __restrict__ bcur2,
    int* __restrict__ offsets, int* __restrict__ srcp,
    unsigned int* __restrict__ tstate, int nb32, int n_nodes, int nregions)
{
  __shared__ int cnt[128];
  __shared__ int cur[128];
  __shared__ int w0tot;
  __shared__ int s_total;
  __shared__ int s_pfx;
  const int b = blockIdx.x;
  const int t = threadIdx.x;
  const int base = b * 128;
  int bb0 = b * 4;
  int bb1 = bb0 + 4; if (bb1 > nb32) bb1 = nb32;

  if (t < 128) cnt[t] = 0;
  __syncthreads();
  for (int bb = bb0; bb < bb1; ++bb) {
    #pragma unroll
    for (int c8 = 0; c8 < 8; ++c8) {
      int segbase = (bb * 8 + c8) * SEG_CAP;
      int fill = bcur2[c8 * nb32 + bb] - segbase;
      for (int j = t; j < fill; j += 256) {
        atomicAdd(&cnt[tmp[segbase + j] >> 16], 1);
      }
    }
  }
  __syncthreads();
  int v = 0, inc = 0;
  if (t < 128) {
    v = cnt[t];
    inc = v;
    #pragma unroll
    for (int off = 1; off < 64; off <<= 1) {
      int u = __shfl_up(inc, off);
      if ((t & 63) >= off) inc += u;
    }
    if (t == 63) w0tot = inc;
    cnt[t] = inc - v;   // within-wave exclusive
  }
  __syncthreads();
  if (t == 127) s_total = cnt[127] + w0tot + v;
  __syncthreads();
  if (t == 0) {
    int total = s_total;
    atomicExch(&tstate[b], 0x40000000u | (unsigned)total);   // PARTIAL
    int prefix = 0;
    int i = b - 1;
    while (i >= 0) {
      unsigned st = atomicAdd(&tstate[i], 0u);
      unsigned fl = st >> 30;
      if (fl == 0u) continue;
      prefix += (int)(st & 0x3FFFFFFFu);
      if (fl == 2u) break;
      --i;
    }
    atomicExch(&tstate[b], 0x80000000u | (unsigned)(prefix + total));  // PREFIX
    s_pfx = prefix;
    if (b == nregions - 1) offsets[n_nodes] = prefix + total;
  }
  __syncthreads();
  if (t < 128) {
    int ex = cnt[t] + ((t >= 64) ? w0tot : 0);
    int node = base + t;
    int off = s_pfx + ex;
    if (node < n_nodes) offsets[node] = off;
    cur[t] = off;
  }
  __syncthreads();
  for (int bb = bb0; bb < bb1; ++bb) {
    #pragma unroll
    for (int c8 = 0; c8 < 8; ++c8) {
      int segbase = (bb * 8 + c8) * SEG_CAP;
      int fill = bcur2[c8 * nb32 + bb] - segbase;
      for (int j = t; j < fill; j += 256) {
        unsigned int q = tmp[segbase + j];
        int p = atomicAdd(&cur[q >> 16], 1);
        srcp[p] = (int)(q & 0xFFFFu);
      }
    }
  }
}

// ---------------- fused score + aggregation (round-20 form) ----------------

#define AGG_E(qj, xj)                                               \
  {                                                                 \
    float f0 = bfbits(qj << 16), f1 = bfbits(qj & 0xFFFF0000u);     \
    a00 = fmaf(xj.x, f0, a00); a01 = fmaf(xj.x, f1, a01);           \
    a10 = fmaf(xj.y, f0, a10); a11 = fmaf(xj.y, f1, a11);           \
  }

__global__ __launch_bounds__(256) void aggregate_kernel(
    const unsigned short* __restrict__ hsrc,   // [N][128] bf16
    const float* __restrict__ el, const float* __restrict__ er,
    const int* __restrict__ srcp, const int* __restrict__ offsets,
    unsigned int* __restrict__ agghi, int n_nodes)
{
  __shared__ int s_s[4][64];
  __shared__ float2 s_x[4][64];
  const int wid = threadIdx.x >> 6;
  const int c = threadIdx.x & 63;
  int node = blockIdx.x * 4 + wid;
  if (node >= n_nodes) return;
  int beg = offsets[node];
  int end = offsets[node + 1];
  float2 ern = *(const float2*)&er[(size_t)node * 2];

  float a00 = 0.f, a01 = 0.f, a10 = 0.f, a11 = 0.f;
  float den0 = 0.f, den1 = 0.f;

  for (int chunk = beg; chunk < end; chunk += 64) {
    int m = end - chunk; if (m > 64) m = 64;
    if (c < m) {
      int s = srcp[chunk + c];
      float2 l = *(const float2*)&el[(size_t)s * 2];
      float e0 = l.x + ern.x;
      float e1 = l.y + ern.y;
      e0 = fminf((e0 >= 0.f) ? e0 : NEG_SLOPE * e0, 60.f);
      e1 = fminf((e1 >= 0.f) ? e1 : NEG_SLOPE * e1, 60.f);
      float x0 = __expf(e0), x1 = __expf(e1);
      den0 += x0; den1 += x1;
      s_s[wid][c] = s;
      s_x[wid][c] = make_float2(x0, x1);
    }
    __builtin_amdgcn_wave_barrier();
    int e = 0;
    for (; e + 8 <= m; e += 8) {
      int s0 = s_s[wid][e + 0], s1 = s_s[wid][e + 1], s2 = s_s[wid][e + 2], s3 = s_s[wid][e + 3];
      int s4 = s_s[wid][e + 4], s5 = s_s[wid][e + 5], s6 = s_s[wid][e + 6], s7 = s_s[wid][e + 7];
      float2 x0 = s_x[wid][e + 0], x1 = s_x[wid][e + 1], x2 = s_x[wid][e + 2], x3 = s_x[wid][e + 3];
      float2 x4 = s_x[wid][e + 4], x5 = s_x[wid][e + 5], x6 = s_x[wid][e + 6], x7 = s_x[wid][e + 7];
      unsigned int q0 = *(const unsigned int*)&hsrc[(size_t)s0 * 128 + c * 2];
      unsigned int q1 = *(const unsigned int*)&hsrc[(size_t)s1 * 128 + c * 2];
      unsigned int q2 = *(const unsigned int*)&hsrc[(size_t)s2 * 128 + c * 2];
      unsigned int q3 = *(const unsigned int*)&hsrc[(size_t)s3 * 128 + c * 2];
      unsigned int q4 = *(const unsigned int*)&hsrc[(size_t)s4 * 128 + c * 2];
      unsigned int q5 = *(const unsigned int*)&hsrc[(size_t)s5 * 128 + c * 2];
      unsigned int q6 = *(const unsigned int*)&hsrc[(size_t)s6 * 128 + c * 2];
      unsigned int q7 = *(const unsigned int*)&hsrc[(size_t)s7 * 128 + c * 2];
      AGG_E(q0, x0)
      AGG_E(q1, x1)
      AGG_E(q2, x2)
      AGG_E(q3, x3)
      AGG_E(q4, x4)
      AGG_E(q5, x5)
      AGG_E(q6, x6)
      AGG_E(q7, x7)
    }
    for (; e < m; ++e) {
      int s0 = s_s[wid][e];
      float2 x0 = s_x[wid][e];
      unsigned int q0 = *(const unsigned int*)&hsrc[(size_t)s0 * 128 + c * 2];
      AGG_E(q0, x0)
    }
    __builtin_amdgcn_wave_barrier();
  }

  #pragma unroll
  for (int off = 32; off > 0; off >>= 1) {
    den0 += __shfl_xor(den0, off);
    den1 += __shfl_xor(den1, off);
  }

  float o00 = 0.f, o01 = 0.f, o10 = 0.f, o11 = 0.f;
  if (end > beg) {
    float i0 = 1.0f / den0, i1 = 1.0f / den1;
    o00 = a00 * i0; o01 = a01 * i0;
    o10 = a10 * i1; o11 = a11 * i1;
  }
  unsigned int hi0 = (unsigned int)f2bf(o00) | ((unsigned int)f2bf(o01) << 16);
  unsigned int hi1 = (unsigned int)f2bf(o10) | ((unsigned int)f2bf(o11) << 16);
  agghi[(size_t)node * 128 + c]      = hi0;
  agghi[(size_t)node * 128 + 64 + c] = hi1;
}

// ---------------- gemm1: hbuf = 0.5*(agg@W0) + bmean; el2/er2 ----------------

__global__ __launch_bounds__(256) void gemm1_kernel(
    const unsigned short* __restrict__ agghi,
    const unsigned short* __restrict__ Whi, const unsigned short* __restrict__ Wlo,
    const float* __restrict__ wal2, const float* __restrict__ war2,
    const float* __restrict__ b0,
    unsigned short* __restrict__ hb16, float* __restrict__ el, float* __restrict__ er,
    int n_nodes)
{
  __shared__ unsigned short lds_bh[16384];
  __shared__ unsigned short lds_bl[16384];
  const int tid = threadIdx.x;
  const int w = tid >> 6;
  const int lane = tid & 63;
  const int lrow = lane & 15;
  const int g = lane >> 4;
  const int node0 = blockIdx.x * 64 + w * 16;

  int arow = node0 + lrow;
  int arow_c = (arow < n_nodes) ? arow : (n_nodes - 1);

  f32x4_t acc[8];
  #pragma unroll
  for (int i = 0; i < 8; ++i) acc[i] = (f32x4_t){0.f, 0.f, 0.f, 0.f};

  for (int hb = 0; hb < 2; ++hb) {
    __syncthreads();
    {
      const uint4* gh = (const uint4*)(Whi + (size_t)hb * 16384);
      const uint4* gl = (const uint4*)(Wlo + (size_t)hb * 16384);
      uint4* lh = (uint4*)lds_bh;
      uint4* ll = (uint4*)lds_bl;
      #pragma unroll
      for (int r = 0; r < 8; ++r) {
        lh[tid + 256 * r] = gh[tid + 256 * r];
        ll[tid + 256 * r] = gl[tid + 256 * r];
      }
    }
    __syncthreads();
    const unsigned short* ah_p = agghi + (size_t)arow_c * 256 + hb * 128 + g * 8;
    #pragma unroll
    for (int s = 0; s < 4; ++s) {
      bf16x8_t ahi = *(const bf16x8_t*)(ah_p + s * 32);
      #pragma unroll
      for (int ct = 0; ct < 8; ++ct) {
        bf16x8_t bh = *(const bf16x8_t*)&lds_bh[((s * 8 + ct) * 64 + lane) * 8];
        bf16x8_t bl = *(const bf16x8_t*)&lds_bl[((s * 8 + ct) * 64 + lane) * 8];
        acc[ct] = __builtin_amdgcn_mfma_f32_16x16x32_bf16(ahi, bh, acc[ct], 0, 0, 0);
        acc[ct] = __builtin_amdgcn_mfma_f32_16x16x32_bf16(ahi, bl, acc[ct], 0, 0, 0);
      }
    }
  }

  float bm[8], alc0[8], alc1[8], arc0[8], arc1[8];
  #pragma unroll
  for (int ct = 0; ct < 8; ++ct) {
    int col = ct * 16 + lrow;
    bm[ct] = 0.5f * (b0[col] + b0[128 + col]);
    alc0[ct] = wal2[col];
    alc1[ct] = wal2[128 + col];
    arc0[ct] = war2[col];
    arc1[ct] = war2[128 + col];
  }
  #pragma unroll
  for (int r = 0; r < 4; ++r) {
    int orow = node0 + g * 4 + r;
    bool ok = orow < n_nodes;
    float pl0 = 0.f, pl1 = 0.f, pr0 = 0.f, pr1 = 0.f;
    #pragma unroll
    for (int ct = 0; ct < 8; ++ct) {
      float v = fmaf(acc[ct][r], 0.5f, bm[ct]);
      pl0 += v * alc0[ct];
      pl1 += v * alc1[ct];
      pr0 += v * arc0[ct];
      pr1 += v * arc1[ct];
      if (ok) hb16[(size_t)orow * 128 + ct * 16 + lrow] = f2bf(v);
    }
    #pragma unroll
    for (int off = 1; off < 16; off <<= 1) {
      pl0 += __shfl_xor(pl0, off);
      pl1 += __shfl_xor(pl1, off);
      pr0 += __shfl_xor(pr0, off);
      pr1 += __shfl_xor(pr1, off);
    }
    if (lrow == 0 && ok) {
      *(float2*)&el[(size_t)orow * 2] = make_float2(pl0, pl1);
      *(float2*)&er[(size_t)orow * 2] = make_float2(pr0, pr1);
    }
  }
}

// ---------------- gemm2: out[:, hb*128:+128] = agg[:,hb,:] @ W1_hb + b1_hb ----

__global__ __launch_bounds__(256) void gemm2_kernel(
    const unsigned short* __restrict__ agghi,
    const unsigned short* __restrict__ Whi, const unsigned short* __restrict__ Wlo,
    const float* __restrict__ b1, float* __restrict__ out, int n_nodes)
{
  __shared__ unsigned short lds_bh[16384];
  __shared__ unsigned short lds_bl[16384];
  const int tid = threadIdx.x;
  const int w = tid >> 6;
  const int lane = tid & 63;
  const int lrow = lane & 15;
  const int g = lane >> 4;
  const int hb = blockIdx.y;
  const int node0 = blockIdx.x * 64 + w * 16;

  {
    const uint4* gh = (const uint4*)(Whi + (size_t)hb * 16384);
    const uint4* gl = (const uint4*)(Wlo + (size_t)hb * 16384);
    uint4* lh = (uint4*)lds_bh;
    uint4* ll = (uint4*)lds_bl;
    #pragma unroll
    for (int r = 0; r < 8; ++r) {
      lh[tid + 256 * r] = gh[tid + 256 * r];
      ll[tid + 256 * r] = gl[tid + 256 * r];
    }
  }

  int arow = node0 + lrow;
  int arow_c = (arow < n_nodes) ? arow : (n_nodes - 1);
  const unsigned short* ah_p = agghi + (size_t)arow_c * 256 + hb * 128 + g * 8;

  f32x4_t acc[8];
  #pragma unroll
  for (int i = 0; i < 8; ++i) acc[i] = (f32x4_t){0.f, 0.f, 0.f, 0.f};

  __syncthreads();

  #pragma unroll
  for (int s = 0; s < 4; ++s) {
    bf16x8_t ahi = *(const bf16x8_t*)(ah_p + s * 32);
    #pragma unroll
    for (int ct = 0; ct < 8; ++ct) {
      bf16x8_t bh = *(const bf16x8_t*)&lds_bh[((s * 8 + ct) * 64 + lane) * 8];
      bf16x8_t bl = *(const bf16x8_t*)&lds_bl[((s * 8 + ct) * 64 + lane) * 8];
      acc[ct] = __builtin_amdgcn_mfma_f32_16x16x32_bf16(ahi, bh, acc[ct], 0, 0, 0);
      acc[ct] = __builtin_amdgcn_mfma_f32_16x16x32_bf16(ahi, bl, acc[ct], 0, 0, 0);
    }
  }

  float bc[8];
  #pragma unroll
  for (int ct = 0; ct < 8; ++ct) bc[ct] = b1[hb * 128 + ct * 16 + lrow];
  #pragma unroll
  for (int r = 0; r < 4; ++r) {
    int orow = node0 + g * 4 + r;
    if (orow >= n_nodes) continue;
    #pragma unroll
    for (int ct = 0; ct < 8; ++ct) {
      out[(size_t)orow * 256 + hb * 128 + ct * 16 + lrow] = acc[ct][r] + bc[ct];
    }
  }
}

// ---------------- launch ----------------

extern "C" void kernel_launch(void* const* d_in, const int* in_sizes, int n_in,
                              void* d_out, int out_size, void* d_ws, size_t ws_size,
                              hipStream_t stream) {
  const float* x   = (const float*)d_in[0];
  const float* Ws  = (const float*)d_in[1];
  const float* als = (const float*)d_in[2];
  const float* ars = (const float*)d_in[3];
  const float* bs  = (const float*)d_in[4];
  const int*   src = (const int*)d_in[5];
  const int*   dst = (const int*)d_in[6];
  const int N = in_sizes[0] / 128;   // 50000
  const int E = in_sizes[5];         // 800000
  float* out = (float*)d_out;

  char* ws = (char*)d_ws;
  auto alloc = [&](size_t bytes) {
    char* p = ws;
    ws += (bytes + 255) & ~(size_t)255;
    return p;
  };
  const int nb32 = (N + 31) / 32;   // 1563 buckets

  unsigned int* agghi = (unsigned int*)alloc((size_t)N * 128 * 4);
  unsigned short* xb16 = (unsigned short*)alloc((size_t)N * 128 * 2);
  unsigned short* hb16 = (unsigned short*)alloc((size_t)N * 128 * 2);
  int*   srcp    = (int*)alloc((size_t)E * 4);
  unsigned int* tmp = (unsigned int*)alloc((size_t)nb32 * 8 * SEG_CAP * 4);  // 8MB
  int*   offsets = (int*)alloc((size_t)(N + 1) * 4);
  int*   bcur2   = (int*)alloc((size_t)nb32 * 8 * 4);
  unsigned int* tstate = (unsigned int*)alloc((size_t)512 * 4);
  float* el      = (float*)alloc((size_t)N * 2 * 4);
  float* er      = (float*)alloc((size_t)N * 2 * 4);
  float* wal     = (float*)alloc((size_t)512 * 4);
  float* war     = (float*)alloc((size_t)512 * 4);
  unsigned short* Whi = (unsigned short*)alloc((size_t)65536 * 2);
  unsigned short* Wlo = (unsigned short*)alloc((size_t)65536 * 2);

  const int init_blocks = 36 + (nb32 * 8 + 255) / 256;
  const int ngrp = (N + 3) / 4;
  const int ntiles = (N + 63) / 64;
  const int nregions = (N + 127) / 128;      // 391
  const int histBlocks2 = (E + 511) / 512;   // 1563

  init_kernel<<<dim3(init_blocks), dim3(256), 0, stream>>>(
      Ws, als, ars, Whi, Wlo, wal, war, bcur2, tstate, N, nb32);
  binAx_kernel<<<dim3(histBlocks2 + ngrp), dim3(256), 0, stream>>>(
      src, dst, bcur2, tmp, nb32, E, histBlocks2, x, wal, war, xb16, el, er, N);
  binB_kernel<<<dim3(nregions), dim3(256), 0, stream>>>(
      tmp, bcur2, offsets, srcp, tstate, nb32, N, nregions);

  // layer 1
  aggregate_kernel<<<dim3(ngrp), dim3(256), 0, stream>>>(
      xb16, el, er, srcp, offsets, agghi, N);
  gemm1_kernel<<<dim3(ntiles), dim3(256), 0, stream>>>(
      (const unsigned short*)agghi, Whi, Wlo, wal + 256, war + 256, bs, hb16, el, er, N);
  // layer 2
  aggregate_kernel<<<dim3(ngrp), dim3(256), 0, stream>>>(
      hb16, el, er, srcp, offsets, agghi, N);
  gemm2_kernel<<<dim3(ntiles, 2), dim3(256), 0, stream>>>(
      (const unsigned short*)agghi, Whi + 32768, Wlo + 32768, bs + 256, out, N);
}

// Round 25
// 170.818 us; speedup vs baseline: 1.2018x; 1.2018x over previous
//
#include <hip/hip_runtime.h>
#include <hip/hip_bf16.h>

// GAT 2-layer, N=50000, E=800000, D=128, H=2, F=128, C=H*F=256.
// Round 25: block-batched multisplit. binA stages 4096 edges in LDS, bins by
// 128-node region via LDS atomics, reserves one global atomicAdd per
// (region, class=blockIdx&7) batch (~77K global atomics vs 800K), scatters
// contiguous batches. binB: region=block, 8 class sub-segments, LDS hist +
// decoupled lookback (r23 form). Aggregate (r20) / gemms byte-identical.

#define NEG_SLOPE 0.2f
#define SEG_CAP 512      // per-(region,class) capacity; mean 256, +16 sigma
#define EPB 4096         // edges per binA block

typedef __attribute__((ext_vector_type(8))) short bf16x8_t;
typedef __attribute__((ext_vector_type(4))) float f32x4_t;

__device__ __forceinline__ unsigned short f2bf(float f) {
  union { float f; unsigned int u; } v; v.f = f;
  unsigned int r = v.u + 0x7FFFu + ((v.u >> 16) & 1u);
  return (unsigned short)(r >> 16);
}
__device__ __forceinline__ float bfbits(unsigned int hi16) {
  union { unsigned int u; float f; } v; v.u = hi16;
  return v.f;
}

// ---------------- init: wpack + wal/war + gcur segment bases + tstate --------

__global__ __launch_bounds__(256) void init_kernel(
    const float* __restrict__ Ws, const float* __restrict__ als,
    const float* __restrict__ ars,
    unsigned short* __restrict__ Whi, unsigned short* __restrict__ Wlo,
    float* __restrict__ wal, float* __restrict__ war,
    int* __restrict__ gcur, unsigned int* __restrict__ tstate,
    int nregions)
{
  const int b = blockIdx.x;
  const int t = threadIdx.x;
  if (b < 32) {
    int tg = b * 256 + t;
    int t2 = tg & 4095;
    int lane = t2 & 63;
    int ct3 = (t2 >> 6) & 7;
    int s = (t2 >> 9) & 3;
    int hb = (t2 >> 11) & 1;
    int lay = tg >> 12;
    int col = hb * 128 + ct3 * 16 + (lane & 15);
    int kbase = s * 32 + (lane >> 4) * 8;
    size_t obase = (size_t)lay * 32768 + (size_t)hb * 16384 + (size_t)(t2 & 2047) * 8;
    #pragma unroll
    for (int j = 0; j < 8; ++j) {
      float w = Ws[(size_t)lay * 32768 + (size_t)(kbase + j) * 256 + col];
      unsigned short hb16 = f2bf(w);
      float rem = w - bfbits((unsigned int)hb16 << 16);
      Whi[obase + j] = hb16;
      Wlo[obase + j] = f2bf(rem);
    }
  } else if (b < 36) {
    int tg = (b - 32) * 256 + t;           // 0..1023
    int lr = tg >> 9;
    int rem = tg & 511;
    int lay = rem >> 8, h = (rem >> 7) & 1, k = rem & 127;
    const float* a = (lr ? ars : als) + (size_t)lay * 256 + h * 128;
    const float* wrow = Ws + (size_t)lay * 32768 + (size_t)k * 256 + h * 128;
    float sum = 0.f;
    for (int f = 0; f < 128; ++f) sum = fmaf(wrow[f], a[f], sum);
    (lr ? war : wal)[(size_t)lay * 256 + h * 128 + k] = sum;
  } else {
    int idx = (b - 36) * 256 + t;
    if (idx < nregions * 8) gcur[idx] = idx * SEG_CAP;   // segment base
    if (idx < 512) tstate[idx] = 0u;
  }
}

// ---------------- binA (block-batched) + xprep fused ----------------
// Blocks [0,binABlocks): stage EPB edges in LDS, LDS-hist by region (d>>7),
// reserve one global atomicAdd per (region, class=b&7), scatter batches.
// Blocks after: xprep (x->bf16 pack + layer-1 el/er).

__global__ __launch_bounds__(256) void binAx_kernel(
    const int* __restrict__ src, const int* __restrict__ dst,
    int* __restrict__ gcur, unsigned int* __restrict__ tmp,
    int n_edges, int binABlocks,
    const float* __restrict__ x, const float* __restrict__ wal,
    const float* __restrict__ war, unsigned short* __restrict__ xb16,
    float* __restrict__ el, float* __restrict__ er, int n)
{
  __shared__ unsigned int ebuf[EPB];
  __shared__ int rcnt[392];
  __shared__ int rbase[392];
  const int b = blockIdx.x;
  const int t = threadIdx.x;
  if (b < binABlocks) {
    const int cls = b & 7;
    const int base = b * EPB;
    int nE = n_edges - base; if (nE > EPB) nE = EPB;
    for (int i = t; i < 392; i += 256) rcnt[i] = 0;
    __syncthreads();
    for (int i = t; i < nE; i += 256) {
      int d = dst[base + i];
      int s = src[base + i];
      ebuf[i] = ((unsigned int)d << 16) | (unsigned int)s;
      atomicAdd(&rcnt[d >> 7], 1);
    }
    __syncthreads();
    for (int r = t; r < 391; r += 256) {
      int cnt = rcnt[r];
      int gb = 0;
      if (cnt > 0) gb = atomicAdd(&gcur[r * 8 + cls], cnt);
      rbase[r] = gb;
      rcnt[r] = 0;
    }
    __syncthreads();
    for (int i = t; i < nE; i += 256) {
      unsigned int q = ebuf[i];
      int d = (int)(q >> 16);
      int r = d >> 7;
      int rank = atomicAdd(&rcnt[r], 1);
      tmp[rbase[r] + rank] = ((unsigned int)(d & 127) << 16) | (q & 0xFFFFu);
    }
    return;
  }
  int node = (b - binABlocks) * 4 + (t >> 6);
  int c = t & 63;
  if (node >= n) return;
  float2 v = *(const float2*)&x[(size_t)node * 128 + c * 2];
  unsigned int pk = (unsigned int)f2bf(v.x) | ((unsigned int)f2bf(v.y) << 16);
  *(unsigned int*)&xb16[(size_t)node * 128 + c * 2] = pk;
  float pl0 = v.x * wal[2 * c] + v.y * wal[2 * c + 1];
  float pl1 = v.x * wal[128 + 2 * c] + v.y * wal[128 + 2 * c + 1];
  float pr0 = v.x * war[2 * c] + v.y * war[2 * c + 1];
  float pr1 = v.x * war[128 + 2 * c] + v.y * war[128 + 2 * c + 1];
  #pragma unroll
  for (int off = 1; off < 64; off <<= 1) {
    pl0 += __shfl_xor(pl0, off);
    pl1 += __shfl_xor(pl1, off);
    pr0 += __shfl_xor(pr0, off);
    pr1 += __shfl_xor(pr1, off);
  }
  if (c == 0) {
    *(float2*)&el[(size_t)node * 2] = make_float2(pl0, pl1);
    *(float2*)&er[(size_t)node * 2] = make_float2(pr0, pr1);
  }
}

// ---------------- binB: fills -> LDS hist -> lookback prefix -> offsets/srcp -
// Block per 128-node region; 8 class sub-segments. tstate[b] = flag|value.

__global__ __launch_bounds__(256) void binB_kernel(
    const unsigned int* __restrict__ tmp, const int* __restrict__ gcur,
    int* __restrict__ offsets, int* __restrict__ srcp,
    unsigned int* __restrict__ tstate, int n_nodes, int nregions)
{
  __shared__ int cnt[128];
  __shared__ int cur[128];
  __shared__ int w0tot;
  __shared__ int s_total;
  __shared__ int s_pfx;
  const int b = blockIdx.x;
  const int t = threadIdx.x;
  const int base = b * 128;

  if (t < 128) cnt[t] = 0;
  __syncthreads();
  #pragma unroll
  for (int c8 = 0; c8 < 8; ++c8) {
    int segbase = (b * 8 + c8) * SEG_CAP;
    int fill = gcur[b * 8 + c8] - segbase;
    for (int j = t; j < fill; j += 256) {
      atomicAdd(&cnt[tmp[segbase + j] >> 16], 1);
    }
  }
  __syncthreads();
  int v = 0, inc = 0;
  if (t < 128) {
    v = cnt[t];
    inc = v;
    #pragma unroll
    for (int off = 1; off < 64; off <<= 1) {
      int u = __shfl_up(inc, off);
      if ((t & 63) >= off) inc += u;
    }
    if (t == 63) w0tot = inc;
    cnt[t] = inc - v;   // within-wave exclusive
  }
  __syncthreads();
  if (t == 127) s_total = cnt[127] + w0tot + v;
  __syncthreads();
  if (t == 0) {
    int total = s_total;
    atomicExch(&tstate[b], 0x40000000u | (unsigned)total);   // PARTIAL
    int prefix = 0;
    int i = b - 1;
    while (i >= 0) {
      unsigned st = atomicAdd(&tstate[i], 0u);
      unsigned fl = st >> 30;
      if (fl == 0u) continue;
      prefix += (int)(st & 0x3FFFFFFFu);
      if (fl == 2u) break;
      --i;
    }
    atomicExch(&tstate[b], 0x80000000u | (unsigned)(prefix + total));  // PREFIX
    s_pfx = prefix;
    if (b == nregions - 1) offsets[n_nodes] = prefix + total;
  }
  __syncthreads();
  if (t < 128) {
    int ex = cnt[t] + ((t >= 64) ? w0tot : 0);
    int node = base + t;
    int off = s_pfx + ex;
    if (node < n_nodes) offsets[node] = off;
    cur[t] = off;
  }
  __syncthreads();
  #pragma unroll
  for (int c8 = 0; c8 < 8; ++c8) {
    int segbase = (b * 8 + c8) * SEG_CAP;
    int fill = gcur[b * 8 + c8] - segbase;
    for (int j = t; j < fill; j += 256) {
      unsigned int q = tmp[segbase + j];
      int p = atomicAdd(&cur[q >> 16], 1);
      srcp[p] = (int)(q & 0xFFFFu);
    }
  }
}

// ---------------- fused score + aggregation (round-20 form) ----------------

#define AGG_E(qj, xj)                                               \
  {                                                                 \
    float f0 = bfbits(qj << 16), f1 = bfbits(qj & 0xFFFF0000u);     \
    a00 = fmaf(xj.x, f0, a00); a01 = fmaf(xj.x, f1, a01);           \
    a10 = fmaf(xj.y, f0, a10); a11 = fmaf(xj.y, f1, a11);           \
  }

__global__ __launch_bounds__(256) void aggregate_kernel(
    const unsigned short* __restrict__ hsrc,   // [N][128] bf16
    const float* __restrict__ el, const float* __restrict__ er,
    const int* __restrict__ srcp, const int* __restrict__ offsets,
    unsigned int* __restrict__ agghi, int n_nodes)
{
  __shared__ int s_s[4][64];
  __shared__ float2 s_x[4][64];
  const int wid = threadIdx.x >> 6;
  const int c = threadIdx.x & 63;
  int node = blockIdx.x * 4 + wid;
  if (node >= n_nodes) return;
  int beg = offsets[node];
  int end = offsets[node + 1];
  float2 ern = *(const float2*)&er[(size_t)node * 2];

  float a00 = 0.f, a01 = 0.f, a10 = 0.f, a11 = 0.f;
  float den0 = 0.f, den1 = 0.f;

  for (int chunk = beg; chunk < end; chunk += 64) {
    int m = end - chunk; if (m > 64) m = 64;
    if (c < m) {
      int s = srcp[chunk + c];
      float2 l = *(const float2*)&el[(size_t)s * 2];
      float e0 = l.x + ern.x;
      float e1 = l.y + ern.y;
      e0 = fminf((e0 >= 0.f) ? e0 : NEG_SLOPE * e0, 60.f);
      e1 = fminf((e1 >= 0.f) ? e1 : NEG_SLOPE * e1, 60.f);
      float x0 = __expf(e0), x1 = __expf(e1);
      den0 += x0; den1 += x1;
      s_s[wid][c] = s;
      s_x[wid][c] = make_float2(x0, x1);
    }
    __builtin_amdgcn_wave_barrier();
    int e = 0;
    for (; e + 8 <= m; e += 8) {
      int s0 = s_s[wid][e + 0], s1 = s_s[wid][e + 1], s2 = s_s[wid][e + 2], s3 = s_s[wid][e + 3];
      int s4 = s_s[wid][e + 4], s5 = s_s[wid][e + 5], s6 = s_s[wid][e + 6], s7 = s_s[wid][e + 7];
      float2 x0 = s_x[wid][e + 0], x1 = s_x[wid][e + 1], x2 = s_x[wid][e + 2], x3 = s_x[wid][e + 3];
      float2 x4 = s_x[wid][e + 4], x5 = s_x[wid][e + 5], x6 = s_x[wid][e + 6], x7 = s_x[wid][e + 7];
      unsigned int q0 = *(const unsigned int*)&hsrc[(size_t)s0 * 128 + c * 2];
      unsigned int q1 = *(const unsigned int*)&hsrc[(size_t)s1 * 128 + c * 2];
      unsigned int q2 = *(const unsigned int*)&hsrc[(size_t)s2 * 128 + c * 2];
      unsigned int q3 = *(const unsigned int*)&hsrc[(size_t)s3 * 128 + c * 2];
      unsigned int q4 = *(const unsigned int*)&hsrc[(size_t)s4 * 128 + c * 2];
      unsigned int q5 = *(const unsigned int*)&hsrc[(size_t)s5 * 128 + c * 2];
      unsigned int q6 = *(const unsigned int*)&hsrc[(size_t)s6 * 128 + c * 2];
      unsigned int q7 = *(const unsigned int*)&hsrc[(size_t)s7 * 128 + c * 2];
      AGG_E(q0, x0)
      AGG_E(q1, x1)
      AGG_E(q2, x2)
      AGG_E(q3, x3)
      AGG_E(q4, x4)
      AGG_E(q5, x5)
      AGG_E(q6, x6)
      AGG_E(q7, x7)
    }
    for (; e < m; ++e) {
      int s0 = s_s[wid][e];
      float2 x0 = s_x[wid][e];
      unsigned int q0 = *(const unsigned int*)&hsrc[(size_t)s0 * 128 + c * 2];
      AGG_E(q0, x0)
    }
    __builtin_amdgcn_wave_barrier();
  }

  #pragma unroll
  for (int off = 32; off > 0; off >>= 1) {
    den0 += __shfl_xor(den0, off);
    den1 += __shfl_xor(den1, off);
  }

  float o00 = 0.f, o01 = 0.f, o10 = 0.f, o11 = 0.f;
  if (end > beg) {
    float i0 = 1.0f / den0, i1 = 1.0f / den1;
    o00 = a00 * i0; o01 = a01 * i0;
    o10 = a10 * i1; o11 = a11 * i1;
  }
  unsigned int hi0 = (unsigned int)f2bf(o00) | ((unsigned int)f2bf(o01) << 16);
  unsigned int hi1 = (unsigned int)f2bf(o10) | ((unsigned int)f2bf(o11) << 16);
  agghi[(size_t)node * 128 + c]      = hi0;
  agghi[(size_t)node * 128 + 64 + c] = hi1;
}

// ---------------- gemm1: hbuf = 0.5*(agg@W0) + bmean; el2/er2 ----------------

__global__ __launch_bounds__(256) void gemm1_kernel(
    const unsigned short* __restrict__ agghi,
    const unsigned short* __restrict__ Whi, const unsigned short* __restrict__ Wlo,
    const float* __restrict__ wal2, const float* __restrict__ war2,
    const float* __restrict__ b0,
    unsigned short* __restrict__ hb16, float* __restrict__ el, float* __restrict__ er,
    int n_nodes)
{
  __shared__ unsigned short lds_bh[16384];
  __shared__ unsigned short lds_bl[16384];
  const int tid = threadIdx.x;
  const int w = tid >> 6;
  const int lane = tid & 63;
  const int lrow = lane & 15;
  const int g = lane >> 4;
  const int node0 = blockIdx.x * 64 + w * 16;

  int arow = node0 + lrow;
  int arow_c = (arow < n_nodes) ? arow : (n_nodes - 1);

  f32x4_t acc[8];
  #pragma unroll
  for (int i = 0; i < 8; ++i) acc[i] = (f32x4_t){0.f, 0.f, 0.f, 0.f};

  for (int hb = 0; hb < 2; ++hb) {
    __syncthreads();
    {
      const uint4* gh = (const uint4*)(Whi + (size_t)hb * 16384);
      const uint4* gl = (const uint4*)(Wlo + (size_t)hb * 16384);
      uint4* lh = (uint4*)lds_bh;
      uint4* ll = (uint4*)lds_bl;
      #pragma unroll
      for (int r = 0; r < 8; ++r) {
        lh[tid + 256 * r] = gh[tid + 256 * r];
        ll[tid + 256 * r] = gl[tid + 256 * r];
      }
    }
    __syncthreads();
    const unsigned short* ah_p = agghi + (size_t)arow_c * 256 + hb * 128 + g * 8;
    #pragma unroll
    for (int s = 0; s < 4; ++s) {
      bf16x8_t ahi = *(const bf16x8_t*)(ah_p + s * 32);
      #pragma unroll
      for (int ct = 0; ct < 8; ++ct) {
        bf16x8_t bh = *(const bf16x8_t*)&lds_bh[((s * 8 + ct) * 64 + lane) * 8];
        bf16x8_t bl = *(const bf16x8_t*)&lds_bl[((s * 8 + ct) * 64 + lane) * 8];
        acc[ct] = __builtin_amdgcn_mfma_f32_16x16x32_bf16(ahi, bh, acc[ct], 0, 0, 0);
        acc[ct] = __builtin_amdgcn_mfma_f32_16x16x32_bf16(ahi, bl, acc[ct], 0, 0, 0);
      }
    }
  }

  float bm[8], alc0[8], alc1[8], arc0[8], arc1[8];
  #pragma unroll
  for (int ct = 0; ct < 8; ++ct) {
    int col = ct * 16 + lrow;
    bm[ct] = 0.5f * (b0[col] + b0[128 + col]);
    alc0[ct] = wal2[col];
    alc1[ct] = wal2[128 + col];
    arc0[ct] = war2[col];
    arc1[ct] = war2[128 + col];
  }
  #pragma unroll
  for (int r = 0; r < 4; ++r) {
    int orow = node0 + g * 4 + r;
    bool ok = orow < n_nodes;
    float pl0 = 0.f, pl1 = 0.f, pr0 = 0.f, pr1 = 0.f;
    #pragma unroll
    for (int ct = 0; ct < 8; ++ct) {
      float v = fmaf(acc[ct][r], 0.5f, bm[ct]);
      pl0 += v * alc0[ct];
      pl1 += v * alc1[ct];
      pr0 += v * arc0[ct];
      pr1 += v * arc1[ct];
      if (ok) hb16[(size_t)orow * 128 + ct * 16 + lrow] = f2bf(v);
    }
    #pragma unroll
    for (int off = 1; off < 16; off <<= 1) {
      pl0 += __shfl_xor(pl0, off);
      pl1 += __shfl_xor(pl1, off);
      pr0 += __shfl_xor(pr0, off);
      pr1 += __shfl_xor(pr1, off);
    }
    if (lrow == 0 && ok) {
      *(float2*)&el[(size_t)orow * 2] = make_float2(pl0, pl1);
      *(float2*)&er[(size_t)orow * 2] = make_float2(pr0, pr1);
    }
  }
}

// ---------------- gemm2: out[:, hb*128:+128] = agg[:,hb,:] @ W1_hb + b1_hb ----

__global__ __launch_bounds__(256) void gemm2_kernel(
    const unsigned short* __restrict__ agghi,
    const unsigned short* __restrict__ Whi, const unsigned short* __restrict__ Wlo,
    const float* __restrict__ b1, float* __restrict__ out, int n_nodes)
{
  __shared__ unsigned short lds_bh[16384];
  __shared__ unsigned short lds_bl[16384];
  const int tid = threadIdx.x;
  const int w = tid >> 6;
  const int lane = tid & 63;
  const int lrow = lane & 15;
  const int g = lane >> 4;
  const int hb = blockIdx.y;
  const int node0 = blockIdx.x * 64 + w * 16;

  {
    const uint4* gh = (const uint4*)(Whi + (size_t)hb * 16384);
    const uint4* gl = (const uint4*)(Wlo + (size_t)hb * 16384);
    uint4* lh = (uint4*)lds_bh;
    uint4* ll = (uint4*)lds_bl;
    #pragma unroll
    for (int r = 0; r < 8; ++r) {
      lh[tid + 256 * r] = gh[tid + 256 * r];
      ll[tid + 256 * r] = gl[tid + 256 * r];
    }
  }

  int arow = node0 + lrow;
  int arow_c = (arow < n_nodes) ? arow : (n_nodes - 1);
  const unsigned short* ah_p = agghi + (size_t)arow_c * 256 + hb * 128 + g * 8;

  f32x4_t acc[8];
  #pragma unroll
  for (int i = 0; i < 8; ++i) acc[i] = (f32x4_t){0.f, 0.f, 0.f, 0.f};

  __syncthreads();

  #pragma unroll
  for (int s = 0; s < 4; ++s) {
    bf16x8_t ahi = *(const bf16x8_t*)(ah_p + s * 32);
    #pragma unroll
    for (int ct = 0; ct < 8; ++ct) {
      bf16x8_t bh = *(const bf16x8_t*)&lds_bh[((s * 8 + ct) * 64 + lane) * 8];
      bf16x8_t bl = *(const bf16x8_t*)&lds_bl[((s * 8 + ct) * 64 + lane) * 8];
      acc[ct] = __builtin_amdgcn_mfma_f32_16x16x32_bf16(ahi, bh, acc[ct], 0, 0, 0);
      acc[ct] = __builtin_amdgcn_mfma_f32_16x16x32_bf16(ahi, bl, acc[ct], 0, 0, 0);
    }
  }

  float bc[8];
  #pragma unroll
  for (int ct = 0; ct < 8; ++ct) bc[ct] = b1[hb * 128 + ct * 16 + lrow];
  #pragma unroll
  for (int r = 0; r < 4; ++r) {
    int orow = node0 + g * 4 + r;
    if (orow >= n_nodes) continue;
    #pragma unroll
    for (int ct = 0; ct < 8; ++ct) {
      out[(size_t)orow * 256 + hb * 128 + ct * 16 + lrow] = acc[ct][r] + bc[ct];
    }
  }
}

// ---------------- launch ----------------

extern "C" void kernel_launch(void* const* d_in, const int* in_sizes, int n_in,
                              void* d_out, int out_size, void* d_ws, size_t ws_size,
                              hipStream_t stream) {
  const float* x   = (const float*)d_in[0];
  const float* Ws  = (const float*)d_in[1];
  const float* als = (const float*)d_in[2];
  const float* ars = (const float*)d_in[3];
  const float* bs  = (const float*)d_in[4];
  const int*   src = (const int*)d_in[5];
  const int*   dst = (const int*)d_in[6];
  const int N = in_sizes[0] / 128;   // 50000
  const int E = in_sizes[5];         // 800000
  float* out = (float*)d_out;

  char* ws = (char*)d_ws;
  auto alloc = [&](size_t bytes) {
    char* p = ws;
    ws += (bytes + 255) & ~(size_t)255;
    return p;
  };
  const int nregions = (N + 127) / 128;   // 391

  unsigned int* agghi = (unsigned int*)alloc((size_t)N * 128 * 4);
  unsigned short* xb16 = (unsigned short*)alloc((size_t)N * 128 * 2);
  unsigned short* hb16 = (unsigned short*)alloc((size_t)N * 128 * 2);
  int*   srcp    = (int*)alloc((size_t)E * 4);
  unsigned int* tmp = (unsigned int*)alloc((size_t)nregions * 8 * SEG_CAP * 4);  // 6.4MB
  int*   offsets = (int*)alloc((size_t)(N + 1) * 4);
  int*   gcur    = (int*)alloc((size_t)nregions * 8 * 4);
  unsigned int* tstate = (unsigned int*)alloc((size_t)512 * 4);
  float* el      = (float*)alloc((size_t)N * 2 * 4);
  float* er      = (float*)alloc((size_t)N * 2 * 4);
  float* wal     = (float*)alloc((size_t)512 * 4);
  float* war     = (float*)alloc((size_t)512 * 4);
  unsigned short* Whi = (unsigned short*)alloc((size_t)65536 * 2);
  unsigned short* Wlo = (unsigned short*)alloc((size_t)65536 * 2);

  const int init_blocks = 36 + (nregions * 8 + 255) / 256;
  const int ngrp = (N + 3) / 4;
  const int ntiles = (N + 63) / 64;
  const int binABlocks = (E + EPB - 1) / EPB;   // 196

  init_kernel<<<dim3(init_blocks), dim3(256), 0, stream>>>(
      Ws, als, ars, Whi, Wlo, wal, war, gcur, tstate, nregions);
  binAx_kernel<<<dim3(binABlocks + ngrp), dim3(256), 0, stream>>>(
      src, dst, gcur, tmp, E, binABlocks, x, wal, war, xb16, el, er, N);
  binB_kernel<<<dim3(nregions), dim3(256), 0, stream>>>(
      tmp, gcur, offsets, srcp, tstate, N, nregions);

  // layer 1
  aggregate_kernel<<<dim3(ngrp), dim3(256), 0, stream>>>(
      xb16, el, er, srcp, offsets, agghi, N);
  gemm1_kernel<<<dim3(ntiles), dim3(256), 0, stream>>>(
      (const unsigned short*)agghi, Whi, Wlo, wal + 256, war + 256, bs, hb16, el, er, N);
  // layer 2
  aggregate_kernel<<<dim3(ngrp), dim3(256), 0, stream>>>(
      hb16, el, er, srcp, offsets, agghi, N);
  gemm2_kernel<<<dim3(ntiles, 2), dim3(256), 0, stream>>>(
      (const unsigned short*)agghi, Whi + 32768, Wlo + 32768, bs + 256, out, N);
}